// Round 5
// baseline (506.308 us; speedup 1.0000x reference)
//
#include <hip/hip_runtime.h>

// SPModel_6846177870356: y = x@W^T + all2all permute. M=28160, N=K=2048.
// DTYPE WORLD (pinned by 5-round bit forensics): inputs FP32 on device
// (harness upcasts the fp16 reference inputs; header lists only bf16/f32/int),
// d_out FP32 read as float32 ("else float*"). R1/R4 finite-1.2e7 vs R2/R3 NaN
// is only consistent with this world + global_load_lds leaving stale LDS in
// this harness -> reg-staged LDS only.
//
// Structure: 128x128 tile, BK=64, 4 waves (2x2) of 64x64, f32 loads -> exact
// fp16 cvt -> LDS, mfma_f32_16x16x32_f16 (f32 accum), barriers both sides of
// ds_write, XCD-bijective swizzle, fused all2all epilogue with f32 stores.

typedef _Float16 f16;
typedef _Float16 f16x4 __attribute__((ext_vector_type(4)));
typedef _Float16 f16x8 __attribute__((ext_vector_type(8)));
typedef float    f32x4 __attribute__((ext_vector_type(4)));

constexpr int Mdim = 28160;   // 8*44*80
constexpr int Ndim = 2048;
constexpr int Kdim = 2048;
constexpr int BM = 128, BN = 128, BK = 64;
constexpr int NWG = (Mdim / BM) * (Ndim / BN);  // 220*16 = 3520 (%8==0)

__global__ __launch_bounds__(256)
void gemm_a2a_kernel(const float* __restrict__ X, const float* __restrict__ W,
                     float* __restrict__ out) {
    __shared__ f16 sA[BM * BK];   // [m][k] row-major fp16, 16 KiB
    __shared__ f16 sB[BN * BK];   // [n][k] row-major fp16, 16 KiB

    const int tid  = threadIdx.x;
    const int lane = tid & 63;
    const int wid  = tid >> 6;
    const int wr   = wid >> 1;
    const int wc   = wid & 1;

    // XCD-aware bijective swizzle (NWG % 8 == 0).
    const int cpx  = NWG >> 3;
    const int tile = (blockIdx.x & 7) * cpx + (blockIdx.x >> 3);
    const int bn   = tile & 15;
    const int bm   = tile >> 4;
    const int row0 = bm * BM;
    const int col0 = bn * BN;

    f32x4 acc[4][4] = {};

    for (int k0 = 0; k0 < Kdim; k0 += BK) {
        // Load f32, convert to fp16 (exact for fp16-originated values) in regs.
        f16x4 ca[8], cb[8];
#pragma unroll
        for (int i = 0; i < 8; ++i) {
            const int e = (i * 256 + tid) * 4;   // element index in 128x64 tile
            const int r = e >> 6;                // 64 elems per row
            const int c = e & 63;                // c % 4 == 0 -> 16B aligned
            const float4 va = *(const float4*)(X + (size_t)(row0 + r) * Kdim + k0 + c);
            const float4 vb = *(const float4*)(W + (size_t)(col0 + r) * Kdim + k0 + c);
            ca[i] = (f16x4){(f16)va.x, (f16)va.y, (f16)va.z, (f16)va.w};
            cb[i] = (f16x4){(f16)vb.x, (f16)vb.y, (f16)vb.z, (f16)vb.w};
        }
        __syncthreads();   // all waves done reading previous LDS contents
#pragma unroll
        for (int i = 0; i < 8; ++i) {
            const int e = (i * 256 + tid) * 4;
            *(f16x4*)&sA[e] = ca[i];   // 8B ds_write, aligned
            *(f16x4*)&sB[e] = cb[i];
        }
        __syncthreads();   // ds_writes visible to all waves

#pragma unroll
        for (int kk = 0; kk < BK; kk += 32) {
            const int kc = kk + (lane >> 4) * 8;  // frag: row=lane&15, k=(lane>>4)*8+j
            f16x8 af[4], bf[4];
#pragma unroll
            for (int f = 0; f < 4; ++f) {
                af[f] = *(const f16x8*)&sA[(wr * 64 + f * 16 + (lane & 15)) * BK + kc];
                bf[f] = *(const f16x8*)&sB[(wc * 64 + f * 16 + (lane & 15)) * BK + kc];
            }
#pragma unroll
            for (int mi = 0; mi < 4; ++mi)
#pragma unroll
                for (int ni = 0; ni < 4; ++ni)
                    acc[mi][ni] = __builtin_amdgcn_mfma_f32_16x16x32_f16(
                        af[mi], bf[ni], acc[mi][ni], 0, 0, 0);
        }
    }

    // Epilogue: C/D col=lane&15 (n), row=(lane>>4)*4+j (m); fused all2all:
    // out[(n>>8)*M*256 + m*256 + (n&255)], plain f32 stores (out is float*).
#pragma unroll
    for (int mi = 0; mi < 4; ++mi) {
#pragma unroll
        for (int ni = 0; ni < 4; ++ni) {
            const int n     = col0 + wc * 64 + ni * 16 + (lane & 15);
            const int rbase = row0 + wr * 64 + mi * 16 + (lane >> 4) * 4;
            const size_t obase = (size_t)(n >> 8) * ((size_t)Mdim * 256) + (n & 255);
#pragma unroll
            for (int j = 0; j < 4; ++j)
                out[obase + (size_t)(rbase + j) * 256] = acc[mi][ni][j];
        }
    }
}

extern "C" void kernel_launch(void* const* d_in, const int* in_sizes, int n_in,
                              void* d_out, int out_size, void* d_ws, size_t ws_size,
                              hipStream_t stream) {
    const float* X = (const float*)d_in[0];
    const float* W = (const float*)d_in[1];
    float* out     = (float*)d_out;
    hipLaunchKernelGGL(gemm_a2a_kernel, dim3(NWG), dim3(256), 0, stream, X, W, out);
}

// Round 7
// 473.217 us; speedup vs baseline: 1.0699x; 1.0699x over previous
//
#include <hip/hip_runtime.h>

// SPModel_6846177870356: y = x@W^T + all2all permute. M=28160, N=K=2048.
// Inputs FP32 (harness-upcast fp16), output FP32. Round 7 = round 6 with the
// cvt_pkrtz type fixed (__fp16 vec -> bit_cast to _Float16 vec).
//  - double-buffered LDS, ONE barrier per K-step; loads for t+1 issued before
//    the barrier and land during compute (T14).
//  - T2 XOR swizzle (byte ^= (row&7)<<4) kills the 16-way ds_read_b128 bank
//    conflict (8.65e7 conflict cycles in round 5).
//  - v_cvt_pkrtz packed f32->f16 (exact for fp16-originated values).
// Tile: 128x128, BK=64, 4 waves (2x2) x 64x64, mfma_f32_16x16x32_f16,
// XCD-bijective swizzle, fused all2all epilogue.

typedef _Float16 f16;
typedef _Float16 f16x2 __attribute__((ext_vector_type(2)));
typedef _Float16 f16x8 __attribute__((ext_vector_type(8)));
typedef float    f32x4 __attribute__((ext_vector_type(4)));

constexpr int Mdim = 28160;   // 8*44*80
constexpr int Ndim = 2048;
constexpr int Kdim = 2048;
constexpr int BM = 128, BN = 128, BK = 64;
constexpr int NWG = (Mdim / BM) * (Ndim / BN);  // 3520 (%8==0)
constexpr int NT  = Kdim / BK;                  // 32

__device__ __forceinline__ f16x8 pack8(const f32x4& lo, const f32x4& hi) {
    f16x2 p0 = __builtin_bit_cast(f16x2, __builtin_amdgcn_cvt_pkrtz(lo[0], lo[1]));
    f16x2 p1 = __builtin_bit_cast(f16x2, __builtin_amdgcn_cvt_pkrtz(lo[2], lo[3]));
    f16x2 p2 = __builtin_bit_cast(f16x2, __builtin_amdgcn_cvt_pkrtz(hi[0], hi[1]));
    f16x2 p3 = __builtin_bit_cast(f16x2, __builtin_amdgcn_cvt_pkrtz(hi[2], hi[3]));
    return (f16x8){p0[0], p0[1], p1[0], p1[1], p2[0], p2[1], p3[0], p3[1]};
}

__global__ __launch_bounds__(256)
void gemm_a2a_kernel(const float* __restrict__ X, const float* __restrict__ W,
                     float* __restrict__ out) {
    __shared__ f16 sA[2][BM * BK];   // 16 KiB each, swizzled layout
    __shared__ f16 sB[2][BN * BK];

    const int tid  = threadIdx.x;
    const int lane = tid & 63;
    const int wid  = tid >> 6;
    const int wr   = wid >> 1;
    const int wc   = wid & 1;

    const int cpx  = NWG >> 3;                       // XCD-bijective swizzle
    const int tile = (blockIdx.x & 7) * cpx + (blockIdx.x >> 3);
    const int bn   = tile & 15;
    const int bm   = tile >> 4;
    const int row0 = bm * BM;
    const int col0 = bn * BN;

    f32x4 acc[4][4] = {};
    f32x4 ra[8], rb[8];   // in-flight staging regs

    // chunk c8 = i*256+tid covers elements [c8*8 .. c8*8+7] of the 128x64 tile
    // (row = c8>>3, cols (c8&7)*8..+7); LDS byte = (c8*16) ^ ((row&7)<<4).
    auto load_tile = [&](int t) {
        const int k0 = t * BK;
#pragma unroll
        for (int i = 0; i < 4; ++i) {
            const int c8 = i * 256 + tid;
            const int r  = c8 >> 3;
            const int cc = (c8 & 7) * 8;
            const float* pa = X + (size_t)(row0 + r) * Kdim + k0 + cc;
            const float* pb = W + (size_t)(col0 + r) * Kdim + k0 + cc;
            ra[2*i]   = *(const f32x4*)pa;
            ra[2*i+1] = *(const f32x4*)(pa + 4);
            rb[2*i]   = *(const f32x4*)pb;
            rb[2*i+1] = *(const f32x4*)(pb + 4);
        }
    };
    auto write_tile = [&](int buf) {
#pragma unroll
        for (int i = 0; i < 4; ++i) {
            const int c8 = i * 256 + tid;
            const int sb = (c8 * 16) ^ (((c8 >> 3) & 7) << 4);
            *(f16x8*)((char*)sA[buf] + sb) = pack8(ra[2*i], ra[2*i+1]);
            *(f16x8*)((char*)sB[buf] + sb) = pack8(rb[2*i], rb[2*i+1]);
        }
    };

    load_tile(0);
    int cur = 0;
    for (int t = 0; t < NT; ++t) {
        write_tile(cur);                    // buf[cur]; others compute buf[cur^1]
        if (t + 1 < NT) load_tile(t + 1);   // in-flight across compute
        __syncthreads();                    // buf[cur] visible

        const f16* Ab = sA[cur];
        const f16* Bb = sB[cur];
#pragma unroll
        for (int kk = 0; kk < BK; kk += 32) {
            const int kc = kk + (lane >> 4) * 8;   // frag row=lane&15, k=(lane>>4)*8+j
            f16x8 af[4], bfr[4];
#pragma unroll
            for (int f = 0; f < 4; ++f) {
                const int rowA = wr * 64 + f * 16 + (lane & 15);
                const int ba   = ((rowA * BK + kc) * 2) ^ ((rowA & 7) << 4);
                af[f] = *(const f16x8*)((const char*)Ab + ba);
                const int rowB = wc * 64 + f * 16 + (lane & 15);
                const int bb   = ((rowB * BK + kc) * 2) ^ ((rowB & 7) << 4);
                bfr[f] = *(const f16x8*)((const char*)Bb + bb);
            }
#pragma unroll
            for (int mi = 0; mi < 4; ++mi)
#pragma unroll
                for (int ni = 0; ni < 4; ++ni)
                    acc[mi][ni] = __builtin_amdgcn_mfma_f32_16x16x32_f16(
                        af[mi], bfr[ni], acc[mi][ni], 0, 0, 0);
        }
        cur ^= 1;
    }

    // Epilogue: C/D col=lane&15 (n), row=(lane>>4)*4+j (m); fused all2all:
    // out[(n>>8)*M*256 + m*256 + (n&255)], f32 stores.
#pragma unroll
    for (int mi = 0; mi < 4; ++mi) {
#pragma unroll
        for (int ni = 0; ni < 4; ++ni) {
            const int n     = col0 + wc * 64 + ni * 16 + (lane & 15);
            const int rbase = row0 + wr * 64 + mi * 16 + (lane >> 4) * 4;
            const size_t obase = (size_t)(n >> 8) * ((size_t)Mdim * 256) + (n & 255);
#pragma unroll
            for (int j = 0; j < 4; ++j)
                out[obase + (size_t)(rbase + j) * 256] = acc[mi][ni][j];
        }
    }
}

extern "C" void kernel_launch(void* const* d_in, const int* in_sizes, int n_in,
                              void* d_out, int out_size, void* d_ws, size_t ws_size,
                              hipStream_t stream) {
    const float* X = (const float*)d_in[0];
    const float* W = (const float*)d_in[1];
    float* out     = (float*)d_out;
    hipLaunchKernelGGL(gemm_a2a_kernel, dim3(NWG), dim3(256), 0, stream, X, W, out);
}